// Round 8
// baseline (280.909 us; speedup 1.0000x reference)
//
#include <hip/hip_runtime.h>
#include <hip/hip_bf16.h>
#include <math.h>

#define S 2048
#define CDIM 1024
#define H 256
#define HS 2048
#define E 16
#define GNUM 4
#define EPG 4
#define TOPK 4
#define KSLICES 8

typedef __attribute__((ext_vector_type(8))) short bfrag_t;   // 8 bf16 = 4 VGPRs
typedef __attribute__((ext_vector_type(4))) float facc_t;    // 4 fp32 acc
typedef __attribute__((ext_vector_type(4))) unsigned int u32x4;

__device__ __forceinline__ float sigmoidf_(float v) { return 1.f / (1.f + __expf(-v)); }

__device__ __forceinline__ unsigned short f2bf(float f) {
    union { float f; unsigned u; } v; v.f = f;
    unsigned r = v.u + 0x7FFFu + ((v.u >> 16) & 1u);   // round-to-nearest-even
    return (unsigned short)(r >> 16);
}
__device__ __forceinline__ float bf2f(unsigned short u) {
    union { unsigned u; float f; } v; v.u = ((unsigned)u) << 16; return v.f;
}

// 16B/lane global->LDS DMA. LDS base is wave-uniform; lane L lands at l + L*16B.
__device__ __forceinline__ void stage16(const unsigned short* g, unsigned short* l, int lane) {
#if __has_builtin(__builtin_amdgcn_global_load_lds)
    __builtin_amdgcn_global_load_lds(
        (const __attribute__((address_space(1))) void*)g,
        (__attribute__((address_space(3))) void*)l, 16, 0, 0);
#else
    *(u32x4*)(l + lane * 8) = *(const u32x4*)g;
#endif
}

// ---------------------------------------------------------------------------
// K1a: split-K router logits. Grid (S/16, 8).
// ---------------------------------------------------------------------------
__global__ __launch_bounds__(256) void logits_kernel(
    const float* __restrict__ x, const float* __restrict__ rw,
    float* __restrict__ lgpart)
{
    const int ks = blockIdx.y;
    const int s0 = blockIdx.x * 16;
    const int tid = threadIdx.x;
    const int t = tid & 15, e = tid >> 4;
    const float4* xp = (const float4*)(x + (size_t)(s0 + t) * CDIM + ks * (CDIM / KSLICES));
    const float4* wp = (const float4*)(rw + (size_t)e * CDIM + ks * (CDIM / KSLICES));
    float acc = 0.f;
#pragma unroll 8
    for (int c = 0; c < CDIM / KSLICES / 4; ++c) {
        float4 xv = xp[c], wv = wp[c];
        acc += xv.x * wv.x + xv.y * wv.y + xv.z * wv.z + xv.w * wv.w;
    }
    lgpart[((size_t)ks * S + s0 + t) * E + e] = acc;
}

// ---------------------------------------------------------------------------
// K1b: route one token per thread.
// ---------------------------------------------------------------------------
__global__ __launch_bounds__(256) void route_kernel(
    const float* __restrict__ lgpart, const float* __restrict__ bias,
    int* __restrict__ counts, int* __restrict__ list, float* __restrict__ wlist)
{
    const int s = blockIdx.x * 256 + threadIdx.x;
    float lgv[E];
#pragma unroll
    for (int i = 0; i < E; ++i) lgv[i] = 0.f;
#pragma unroll
    for (int ks = 0; ks < KSLICES; ++ks) {
        const float4* p = (const float4*)(lgpart + ((size_t)ks * S + s) * E);
#pragma unroll
        for (int q = 0; q < 4; ++q) {
            float4 v = p[q];
            lgv[q * 4 + 0] += v.x; lgv[q * 4 + 1] += v.y;
            lgv[q * 4 + 2] += v.z; lgv[q * 4 + 3] += v.w;
        }
    }
    float sc[E], sb[E];
#pragma unroll
    for (int e2 = 0; e2 < E; ++e2) {
        sc[e2] = 1.f / (1.f + __expf(-lgv[e2]));
        sb[e2] = sc[e2] + bias[e2];
    }
    float gsc[GNUM];
#pragma unroll
    for (int g = 0; g < GNUM; ++g) {
        int b_ = g * EPG;
        int m1 = 0; float v1 = sb[b_];
#pragma unroll
        for (int j = 1; j < EPG; ++j) if (sb[b_ + j] > v1) { v1 = sb[b_ + j]; m1 = j; }
        float v2 = -1e30f;
#pragma unroll
        for (int j = 0; j < EPG; ++j) if (j != m1 && sb[b_ + j] > v2) v2 = sb[b_ + j];
        gsc[g] = v1 + v2;
    }
    int g1 = 0;
#pragma unroll
    for (int g = 1; g < GNUM; ++g) if (gsc[g] > gsc[g1]) g1 = g;
    int g2 = (g1 == 0) ? 1 : 0;
#pragma unroll
    for (int g = 0; g < GNUM; ++g) if (g != g1 && gsc[g] > gsc[g2]) g2 = g;
    bool allowed[E];
#pragma unroll
    for (int e2 = 0; e2 < E; ++e2) {
        int g = e2 >> 2;
        allowed[e2] = (g == g1) || (g == g2);
    }
    int idx[TOPK]; float wk[TOPK];
#pragma unroll
    for (int k = 0; k < TOPK; ++k) {
        int best = 0; float bv = -1e30f;
#pragma unroll
        for (int e2 = 0; e2 < E; ++e2)
            if (allowed[e2] && sb[e2] > bv) { bv = sb[e2]; best = e2; }
        allowed[best] = false;
        idx[k] = best;
        wk[k] = sc[best];
    }
    float inv = 1.f / (wk[0] + wk[1] + wk[2] + wk[3] + 1e-20f);
#pragma unroll
    for (int k = 0; k < TOPK; ++k) {
        int ee = idx[k];
        int pos = atomicAdd(&counts[ee], 1);
        list[ee * S + pos] = s | (k << 16);
        wlist[ee * S + pos] = wk[k] * inv;
    }
}

// ---------------------------------------------------------------------------
// K2: merged fp32 -> bf16 cast of 4 equal-size (2M elem) buffers.
// ---------------------------------------------------------------------------
struct CastArgs {
    const float4* src[4];
    unsigned long long* dst[4];
};
__global__ __launch_bounds__(256) void cast_bf16_x4(CastArgs a, int n4)
{
    int i = blockIdx.x * 256 + threadIdx.x;
    if (i >= n4) return;
    const float4* src = a.src[blockIdx.y];
    float4 v = src[i];
    unsigned long long p = (unsigned long long)f2bf(v.x)
                         | ((unsigned long long)f2bf(v.y) << 16)
                         | ((unsigned long long)f2bf(v.z) << 32)
                         | ((unsigned long long)f2bf(v.w) << 48);
    a.dst[blockIdx.y][i] = p;
}

// ---------------------------------------------------------------------------
// K3: tiled transpose + cast: src [z][R][Cc] fp32 -> dst [z][Cc][R] bf16.
// ---------------------------------------------------------------------------
__global__ __launch_bounds__(256) void transpose_cast2(
    const float* __restrict__ srcA, unsigned short* __restrict__ dstA,
    const float* __restrict__ srcB, unsigned short* __restrict__ dstB,
    int R, int Cc, int nz)
{
    __shared__ float t[32][33];
    int z = blockIdx.z;
    const float* src = (z < nz) ? srcA : srcB;
    unsigned short* dst = (z < nz) ? dstA : dstB;
    if (z >= nz) z -= nz;
    const size_t mo = (size_t)z * R * Cc;
    src += mo; dst += mo;
    const int c0 = blockIdx.x * 32, r0 = blockIdx.y * 32;
    const int tx = threadIdx.x, ty = threadIdx.y;  // (32, 8)
#pragma unroll
    for (int i = 0; i < 32; i += 8)
        t[ty + i][tx] = src[(size_t)(r0 + ty + i) * Cc + c0 + tx];
    __syncthreads();
#pragma unroll
    for (int i = 0; i < 32; i += 8)
        dst[(size_t)(c0 + ty + i) * R + r0 + tx] = f2bf(t[tx][ty + i]);
}

// ---------------------------------------------------------------------------
// m97-style MFMA GEMMs, all BM=128: global_load_lds(16B) staging, unpadded
// [rows][32] LDS with XOR seg swizzle, 2-barrier K-loop, 16 MFMA / 3-4 DMAs
// per K-step. Wave layout 2x2: wave covers 64 rows x 32 cols.
// ---------------------------------------------------------------------------

// K4: shared gate+up fused SwiGLU -> shb bf16 [S][HS]. grid (HS/64, S/128).
__global__ __launch_bounds__(256) void gemm_shared_gateup(
    const unsigned short* __restrict__ xb, const unsigned short* __restrict__ gb,
    const unsigned short* __restrict__ ub, unsigned short* __restrict__ shb)
{
    __shared__ __align__(16) unsigned short As[128 * 32];
    __shared__ __align__(16) unsigned short Bg[64 * 32];
    __shared__ __align__(16) unsigned short Bu[64 * 32];
    const int tid = threadIdx.x;
    const int lane = tid & 63, w = tid >> 6;
    const int l15 = lane & 15, q = lane >> 4;
    const int r0 = blockIdx.y * 128;
    const int c0 = blockIdx.x * 64;
    const int wr = (w >> 1) * 64, wc = (w & 1) * 32;
    const int Lrow = lane >> 2;
    const int gseg = (lane & 3) ^ ((lane >> 3) & 3);
    const unsigned short* gA1 = xb + (size_t)(r0 + w * 16 + Lrow) * CDIM + gseg * 8;
    const unsigned short* gA2 = gA1 + (size_t)64 * CDIM;
    const unsigned short* gG  = gb + (size_t)(c0 + w * 16 + Lrow) * CDIM + gseg * 8;
    const unsigned short* gU  = ub + (size_t)(c0 + w * 16 + Lrow) * CDIM + gseg * 8;
    unsigned short* lA1 = &As[(w * 16) * 32];
    unsigned short* lA2 = lA1 + 64 * 32;
    unsigned short* lG  = &Bg[(w * 16) * 32];
    unsigned short* lU  = &Bu[(w * 16) * 32];
    const int swq = (q ^ ((l15 >> 1) & 3)) * 8;
    facc_t accg[4][2], accu[4][2];
#pragma unroll
    for (int i = 0; i < 4; ++i)
#pragma unroll
        for (int j = 0; j < 2; ++j) { accg[i][j] = 0.f; accu[i][j] = 0.f; }
    for (int k0 = 0; k0 < CDIM; k0 += 32) {
        stage16(gA1 + k0, lA1, lane);
        stage16(gA2 + k0, lA2, lane);
        stage16(gG + k0, lG, lane);
        stage16(gU + k0, lU, lane);
        __syncthreads();
        bfrag_t af[4], gf[2], uf[2];
#pragma unroll
        for (int i = 0; i < 4; ++i)
            af[i] = *(const bfrag_t*)&As[(wr + i * 16 + l15) * 32 + swq];
#pragma unroll
        for (int j = 0; j < 2; ++j) {
            gf[j] = *(const bfrag_t*)&Bg[(wc + j * 16 + l15) * 32 + swq];
            uf[j] = *(const bfrag_t*)&Bu[(wc + j * 16 + l15) * 32 + swq];
        }
#pragma unroll
        for (int i = 0; i < 4; ++i)
#pragma unroll
            for (int j = 0; j < 2; ++j) {
                accg[i][j] = __builtin_amdgcn_mfma_f32_16x16x32_bf16(af[i], gf[j], accg[i][j], 0, 0, 0);
                accu[i][j] = __builtin_amdgcn_mfma_f32_16x16x32_bf16(af[i], uf[j], accu[i][j], 0, 0, 0);
            }
        __syncthreads();
    }
#pragma unroll
    for (int i = 0; i < 4; ++i)
#pragma unroll
        for (int j = 0; j < 2; ++j)
#pragma unroll
            for (int r = 0; r < 4; ++r) {
                int row = r0 + wr + i * 16 + q * 4 + r;
                int col = c0 + wc + j * 16 + l15;
                float g = accg[i][j][r], u = accu[i][j][r];
                shb[(size_t)row * HS + col] = f2bf(g * sigmoidf_(g) * u);
            }
}

// K5: shared down-proj -> out fp32 [S][CDIM]. BM=128/BN=64, K=HS.
// grid (CDIM/64=16, S/128=16).
__global__ __launch_bounds__(256) void gemm_shared_down(
    const unsigned short* __restrict__ shb, const unsigned short* __restrict__ db,
    float* __restrict__ out)
{
    __shared__ __align__(16) unsigned short As[128 * 32];
    __shared__ __align__(16) unsigned short Bs[64 * 32];
    const int tid = threadIdx.x;
    const int lane = tid & 63, w = tid >> 6;
    const int l15 = lane & 15, q = lane >> 4;
    const int r0 = blockIdx.y * 128;
    const int c0 = blockIdx.x * 64;
    const int wr = (w >> 1) * 64, wc = (w & 1) * 32;
    const int Lrow = lane >> 2;
    const int gseg = (lane & 3) ^ ((lane >> 3) & 3);
    const unsigned short* gA1 = shb + (size_t)(r0 + w * 16 + Lrow) * HS + gseg * 8;
    const unsigned short* gA2 = gA1 + (size_t)64 * HS;
    const unsigned short* gB  = db + (size_t)(c0 + w * 16 + Lrow) * HS + gseg * 8;
    unsigned short* lA1 = &As[(w * 16) * 32];
    unsigned short* lA2 = lA1 + 64 * 32;
    unsigned short* lB  = &Bs[(w * 16) * 32];
    const int swq = (q ^ ((l15 >> 1) & 3)) * 8;
    facc_t acc[4][2];
#pragma unroll
    for (int i = 0; i < 4; ++i)
#pragma unroll
        for (int j = 0; j < 2; ++j) acc[i][j] = 0.f;
    for (int k0 = 0; k0 < HS; k0 += 32) {
        stage16(gA1 + k0, lA1, lane);
        stage16(gA2 + k0, lA2, lane);
        stage16(gB + k0, lB, lane);
        __syncthreads();
        bfrag_t af[4], bf[2];
#pragma unroll
        for (int i = 0; i < 4; ++i) af[i] = *(const bfrag_t*)&As[(wr + i * 16 + l15) * 32 + swq];
#pragma unroll
        for (int j = 0; j < 2; ++j) bf[j] = *(const bfrag_t*)&Bs[(wc + j * 16 + l15) * 32 + swq];
#pragma unroll
        for (int i = 0; i < 4; ++i)
#pragma unroll
            for (int j = 0; j < 2; ++j)
                acc[i][j] = __builtin_amdgcn_mfma_f32_16x16x32_bf16(af[i], bf[j], acc[i][j], 0, 0, 0);
        __syncthreads();
    }
#pragma unroll
    for (int i = 0; i < 4; ++i)
#pragma unroll
        for (int j = 0; j < 2; ++j)
#pragma unroll
            for (int r = 0; r < 4; ++r) {
                int row = r0 + wr + i * 16 + q * 4 + r;
                int col = c0 + wc + j * 16 + l15;
                out[(size_t)row * CDIM + col] = acc[i][j][r];
            }
}

// K6: routed gate+up, gathered A rows (BM=128 tokens), weighted SwiGLU ->
// hbuf bf16 [S*4][H]. grid (E, H/64=4, S/128=16); expert-major for XCD L2.
__global__ __launch_bounds__(256) void gemm_routed_gateup(
    const unsigned short* __restrict__ xb, const unsigned short* __restrict__ gwT,
    const unsigned short* __restrict__ uwT, const int* __restrict__ counts,
    const int* __restrict__ list, const float* __restrict__ wlist,
    unsigned short* __restrict__ hbuf)
{
    const int e = blockIdx.x;
    const int n = counts[e];
    const int t0 = blockIdx.z * 128;
    if (t0 >= n) return;
    const int h0 = blockIdx.y * 64;
    __shared__ int toks[128];
    __shared__ int hrw[128];
    __shared__ float wv[128];
    __shared__ __align__(16) unsigned short As[128 * 32];
    __shared__ __align__(16) unsigned short Bg[64 * 32];
    __shared__ __align__(16) unsigned short Bu[64 * 32];
    const int tid = threadIdx.x;
    if (tid < 128) {
        int p = t0 + tid;
        if (p < n) {
            int pk = list[e * S + p];
            toks[tid] = pk & 0xFFFF;
            hrw[tid] = (pk & 0xFFFF) * TOPK + (pk >> 16);
            wv[tid] = wlist[e * S + p];
        } else { toks[tid] = 0; hrw[tid] = 0; wv[tid] = 0.f; }
    }
    __syncthreads();
    const int lane = tid & 63, w = tid >> 6;
    const int l15 = lane & 15, q = lane >> 4;
    const int wr = (w >> 1) * 64, wc = (w & 1) * 32;
    const int Lrow = lane >> 2;
    const int gseg = (lane & 3) ^ ((lane >> 3) & 3);
    const unsigned short* gA1 = xb + (size_t)toks[w * 16 + Lrow] * CDIM + gseg * 8;
    const unsigned short* gA2 = xb + (size_t)toks[64 + w * 16 + Lrow] * CDIM + gseg * 8;
    const unsigned short* gG = gwT + ((size_t)e * H + h0 + w * 16 + Lrow) * CDIM + gseg * 8;
    const unsigned short* gU = uwT + ((size_t)e * H + h0 + w * 16 + Lrow) * CDIM + gseg * 8;
    unsigned short* lA1 = &As[(w * 16) * 32];
    unsigned short* lA2 = lA1 + 64 * 32;
    unsigned short* lG = &Bg[(w * 16) * 32];
    unsigned short* lU = &Bu[(w * 16) * 32];
    const int swq = (q ^ ((l15 >> 1) & 3)) * 8;
    facc_t accg[4][2], accu[4][2];
#pragma unroll
    for (int i = 0; i < 4; ++i)
#pragma unroll
        for (int j = 0; j < 2; ++j) { accg[i][j] = 0.f; accu[i][j] = 0.f; }
    for (int k0 = 0; k0 < CDIM; k0 += 32) {
        stage16(gA1 + k0, lA1, lane);
        stage16(gA2 + k0, lA2, lane);
        stage16(gG + k0, lG, lane);
        stage16(gU + k0, lU, lane);
        __syncthreads();
        bfrag_t af[4], gf[2], uf[2];
#pragma unroll
        for (int i = 0; i < 4; ++i) af[i] = *(const bfrag_t*)&As[(wr + i * 16 + l15) * 32 + swq];
#pragma unroll
        for (int j = 0; j < 2; ++j) {
            gf[j] = *(const bfrag_t*)&Bg[(wc + j * 16 + l15) * 32 + swq];
            uf[j] = *(const bfrag_t*)&Bu[(wc + j * 16 + l15) * 32 + swq];
        }
#pragma unroll
        for (int i = 0; i < 4; ++i)
#pragma unroll
            for (int j = 0; j < 2; ++j) {
                accg[i][j] = __builtin_amdgcn_mfma_f32_16x16x32_bf16(af[i], gf[j], accg[i][j], 0, 0, 0);
                accu[i][j] = __builtin_amdgcn_mfma_f32_16x16x32_bf16(af[i], uf[j], accu[i][j], 0, 0, 0);
            }
        __syncthreads();
    }
#pragma unroll
    for (int i = 0; i < 4; ++i)
#pragma unroll
        for (int j = 0; j < 2; ++j)
#pragma unroll
            for (int r = 0; r < 4; ++r) {
                int li = wr + i * 16 + q * 4 + r;
                if (t0 + li < n) {
                    int col = h0 + wc + j * 16 + l15;
                    float g = accg[i][j][r], u = accu[i][j][r];
                    hbuf[(size_t)hrw[li] * H + col] = f2bf(wv[li] * g * sigmoidf_(g) * u);
                }
            }
}

// K7: routed down-proj -> dbuf bf16 [S*4][CDIM]. BM=128, K=H=256 (8 steps).
// grid (E, CDIM/64=16, S/128=16); expert-major for XCD L2.
__global__ __launch_bounds__(256) void gemm_routed_down(
    const unsigned short* __restrict__ hbuf, const unsigned short* __restrict__ dwT,
    const int* __restrict__ counts, const int* __restrict__ list,
    unsigned short* __restrict__ dbuf)
{
    const int e = blockIdx.x;
    const int n = counts[e];
    const int t0 = blockIdx.z * 128;
    if (t0 >= n) return;
    const int c0 = blockIdx.y * 64;
    __shared__ int hrw[128];
    __shared__ __align__(16) unsigned short As[128 * 32];
    __shared__ __align__(16) unsigned short Bs[64 * 32];
    const int tid = threadIdx.x;
    if (tid < 128) {
        int p = t0 + tid;
        int pk = (p < n) ? list[e * S + p] : 0;
        hrw[tid] = (pk & 0xFFFF) * TOPK + (pk >> 16);
    }
    __syncthreads();
    const int lane = tid & 63, w = tid >> 6;
    const int l15 = lane & 15, q = lane >> 4;
    const int wr = (w >> 1) * 64, wc = (w & 1) * 32;
    const int Lrow = lane >> 2;
    const int gseg = (lane & 3) ^ ((lane >> 3) & 3);
    const unsigned short* gA1 = hbuf + (size_t)hrw[w * 16 + Lrow] * H + gseg * 8;
    const unsigned short* gA2 = hbuf + (size_t)hrw[64 + w * 16 + Lrow] * H + gseg * 8;
    const unsigned short* gB = dwT + ((size_t)e * CDIM + c0 + w * 16 + Lrow) * H + gseg * 8;
    unsigned short* lA1 = &As[(w * 16) * 32];
    unsigned short* lA2 = lA1 + 64 * 32;
    unsigned short* lB = &Bs[(w * 16) * 32];
    const int swq = (q ^ ((l15 >> 1) & 3)) * 8;
    facc_t acc[4][2];
#pragma unroll
    for (int i = 0; i < 4; ++i)
#pragma unroll
        for (int j = 0; j < 2; ++j) acc[i][j] = 0.f;
    for (int k0 = 0; k0 < H; k0 += 32) {
        stage16(gA1 + k0, lA1, lane);
        stage16(gA2 + k0, lA2, lane);
        stage16(gB + k0, lB, lane);
        __syncthreads();
        bfrag_t af[4], bf[2];
#pragma unroll
        for (int i = 0; i < 4; ++i) af[i] = *(const bfrag_t*)&As[(wr + i * 16 + l15) * 32 + swq];
#pragma unroll
        for (int j = 0; j < 2; ++j) bf[j] = *(const bfrag_t*)&Bs[(wc + j * 16 + l15) * 32 + swq];
#pragma unroll
        for (int i = 0; i < 4; ++i)
#pragma unroll
            for (int j = 0; j < 2; ++j)
                acc[i][j] = __builtin_amdgcn_mfma_f32_16x16x32_bf16(af[i], bf[j], acc[i][j], 0, 0, 0);
        __syncthreads();
    }
#pragma unroll
    for (int i = 0; i < 4; ++i)
#pragma unroll
        for (int j = 0; j < 2; ++j)
#pragma unroll
            for (int r = 0; r < 4; ++r) {
                int li = wr + i * 16 + q * 4 + r;
                if (t0 + li < n) {
                    int col = c0 + wc + j * 16 + l15;
                    dbuf[(size_t)hrw[li] * CDIM + col] = f2bf(acc[i][j][r]);
                }
            }
}

// K8: out[s,c] += sum_k dbuf[s*4+k, c]
__global__ __launch_bounds__(256) void final_add(
    float* __restrict__ out, const unsigned short* __restrict__ dbuf)
{
    int i = blockIdx.x * 256 + threadIdx.x;   // 8 floats per thread
    int s = i >> 7;
    int co = (i & 127) << 3;
    float* op = out + (size_t)s * CDIM + co;
    float4 o0 = *(float4*)op, o1 = *(float4*)(op + 4);
#pragma unroll
    for (int k = 0; k < TOPK; ++k) {
        const unsigned short* dp = dbuf + ((size_t)s * TOPK + k) * CDIM + co;
        u32x4 v = *(const u32x4*)dp;
        o0.x += bf2f((unsigned short)(v.x));        o0.y += bf2f((unsigned short)(v.x >> 16));
        o0.z += bf2f((unsigned short)(v.y));        o0.w += bf2f((unsigned short)(v.y >> 16));
        o1.x += bf2f((unsigned short)(v.z));        o1.y += bf2f((unsigned short)(v.z >> 16));
        o1.z += bf2f((unsigned short)(v.w));        o1.w += bf2f((unsigned short)(v.w >> 16));
    }
    *(float4*)op = o0; *(float4*)(op + 4) = o1;
}

// ---------------------------------------------------------------------------
extern "C" void kernel_launch(void* const* d_in, const int* in_sizes, int n_in,
                              void* d_out, int out_size, void* d_ws, size_t ws_size,
                              hipStream_t stream)
{
    const float* x        = (const float*)d_in[0];
    const float* router_w = (const float*)d_in[1];
    const float* bias     = (const float*)d_in[2];
    const float* gate_w   = (const float*)d_in[3];
    const float* up_w     = (const float*)d_in[4];
    const float* down_w   = (const float*)d_in[5];
    const float* sgw      = (const float*)d_in[6];
    const float* suw      = (const float*)d_in[7];
    const float* sdw      = (const float*)d_in[8];
    float* out = (float*)d_out;

    char* ws = (char*)d_ws;
    size_t off = 0;
    int* counts = (int*)(ws + off);            off += 256;
    int* list   = (int*)(ws + off);            off += (size_t)E * S * 4;
    float* wlist = (float*)(ws + off);         off += (size_t)E * S * 4;
    unsigned short* xb  = (unsigned short*)(ws + off); off += (size_t)S * CDIM * 2;
    unsigned short* sgb = (unsigned short*)(ws + off); off += (size_t)HS * CDIM * 2;
    unsigned short* sub = (unsigned short*)(ws + off); off += (size_t)HS * CDIM * 2;
    unsigned short* sdb = (unsigned short*)(ws + off); off += (size_t)CDIM * HS * 2;
    unsigned short* gwT = (unsigned short*)(ws + off); off += (size_t)E * H * CDIM * 2;
    unsigned short* uwT = (unsigned short*)(ws + off); off += (size_t)E * H * CDIM * 2;
    unsigned short* dwT = (unsigned short*)(ws + off); off += (size_t)E * CDIM * H * 2;
    unsigned short* shb = (unsigned short*)(ws + off); off += (size_t)S * HS * 2;
    unsigned short* hbuf = (unsigned short*)(ws + off); off += (size_t)S * TOPK * H * 2;
    unsigned short* dbuf = (unsigned short*)(ws + off); off += (size_t)S * TOPK * CDIM * 2;
    // lgpart (8*S*E floats = 1 MiB) aliases dbuf (consumed before dbuf writes)
    float* lgpart = (float*)dbuf;

    hipMemsetAsync(counts, 0, E * sizeof(int), stream);
    logits_kernel<<<dim3(S / 16, KSLICES), 256, 0, stream>>>(x, router_w, lgpart);
    route_kernel<<<S / 256, 256, 0, stream>>>(lgpart, bias, counts, list, wlist);

    CastArgs ca;
    ca.src[0] = (const float4*)x;   ca.dst[0] = (unsigned long long*)xb;
    ca.src[1] = (const float4*)sgw; ca.dst[1] = (unsigned long long*)sgb;
    ca.src[2] = (const float4*)suw; ca.dst[2] = (unsigned long long*)sub;
    ca.src[3] = (const float4*)sdw; ca.dst[3] = (unsigned long long*)sdb;
    cast_bf16_x4<<<dim3(S * CDIM / 4 / 256, 4), 256, 0, stream>>>(ca, S * CDIM / 4);

    transpose_cast2<<<dim3(H / 32, CDIM / 32, 2 * E), dim3(32, 8), 0, stream>>>(
        gate_w, gwT, up_w, uwT, CDIM, H, E);
    transpose_cast2<<<dim3(CDIM / 32, H / 32, E), dim3(32, 8), 0, stream>>>(
        down_w, dwT, down_w, dwT, H, CDIM, E);

    gemm_shared_gateup<<<dim3(HS / 64, S / 128), 256, 0, stream>>>(xb, sgb, sub, shb);
    gemm_shared_down<<<dim3(CDIM / 64, S / 128), 256, 0, stream>>>(shb, sdb, out);
    gemm_routed_gateup<<<dim3(E, H / 64, S / 128), 256, 0, stream>>>(xb, gwT, uwT, counts, list, wlist, hbuf);
    gemm_routed_down<<<dim3(E, CDIM / 64, S / 128), 256, 0, stream>>>(hbuf, dwT, counts, list, dbuf);
    final_add<<<S * CDIM / 8 / 256, 256, 0, stream>>>(out, dbuf);
}

// Round 9
// 267.720 us; speedup vs baseline: 1.0493x; 1.0493x over previous
//
#include <hip/hip_runtime.h>
#include <hip/hip_bf16.h>
#include <math.h>

#define S 2048
#define CDIM 1024
#define H 256
#define HS 2048
#define E 16
#define GNUM 4
#define EPG 4
#define TOPK 4
#define KSLICES 8

typedef __attribute__((ext_vector_type(8))) short bfrag_t;   // 8 bf16 = 4 VGPRs
typedef __attribute__((ext_vector_type(4))) float facc_t;    // 4 fp32 acc
typedef __attribute__((ext_vector_type(4))) unsigned int u32x4;

__device__ __forceinline__ float sigmoidf_(float v) { return 1.f / (1.f + __expf(-v)); }

__device__ __forceinline__ unsigned short f2bf(float f) {
    union { float f; unsigned u; } v; v.f = f;
    unsigned r = v.u + 0x7FFFu + ((v.u >> 16) & 1u);   // round-to-nearest-even
    return (unsigned short)(r >> 16);
}
__device__ __forceinline__ float bf2f(unsigned short u) {
    union { unsigned u; float f; } v; v.u = ((unsigned)u) << 16; return v.f;
}
__device__ __forceinline__ unsigned long long pack4(float4 v) {
    return (unsigned long long)f2bf(v.x)
         | ((unsigned long long)f2bf(v.y) << 16)
         | ((unsigned long long)f2bf(v.z) << 32)
         | ((unsigned long long)f2bf(v.w) << 48);
}

// 16B/lane global->LDS DMA. LDS base is wave-uniform; lane L lands at l + L*16B.
__device__ __forceinline__ void stage16(const unsigned short* g, unsigned short* l, int lane) {
#if __has_builtin(__builtin_amdgcn_global_load_lds)
    __builtin_amdgcn_global_load_lds(
        (const __attribute__((address_space(1))) void*)g,
        (__attribute__((address_space(3))) void*)l, 16, 0, 0);
#else
    *(u32x4*)(l + lane * 8) = *(const u32x4*)g;
#endif
}

// ---------------------------------------------------------------------------
// K1a: split-K router logits + fused x->bf16 cast. Grid (S/16, 8).
// Thread (t,e) dots token s0+t against expert e over slice ks, then re-loads
// its 8-elem sub-slice (L1-hot) and stores it to xb as bf16.
// ---------------------------------------------------------------------------
__global__ __launch_bounds__(256) void logits_kernel(
    const float* __restrict__ x, const float* __restrict__ rw,
    float* __restrict__ lgpart, unsigned short* __restrict__ xb)
{
    const int ks = blockIdx.y;
    const int s0 = blockIdx.x * 16;
    const int tid = threadIdx.x;
    const int t = tid & 15, e = tid >> 4;
    const float4* xp = (const float4*)(x + (size_t)(s0 + t) * CDIM + ks * (CDIM / KSLICES));
    const float4* wp = (const float4*)(rw + (size_t)e * CDIM + ks * (CDIM / KSLICES));
    float acc = 0.f;
#pragma unroll 8
    for (int c = 0; c < CDIM / KSLICES / 4; ++c) {
        float4 xv = xp[c], wv = wp[c];
        acc += xv.x * wv.x + xv.y * wv.y + xv.z * wv.z + xv.w * wv.w;
    }
    // fused cast: 8 elems per thread, 16B store
    float4 v0 = xp[e * 2], v1 = xp[e * 2 + 1];
    unsigned long long* dst = (unsigned long long*)
        (xb + (size_t)(s0 + t) * CDIM + ks * (CDIM / KSLICES) + e * 8);
    dst[0] = pack4(v0);
    dst[1] = pack4(v1);
    lgpart[((size_t)ks * S + s0 + t) * E + e] = acc;
}

// ---------------------------------------------------------------------------
// K1b: route one token per thread.
// ---------------------------------------------------------------------------
__global__ __launch_bounds__(256) void route_kernel(
    const float* __restrict__ lgpart, const float* __restrict__ bias,
    int* __restrict__ counts, int* __restrict__ list, float* __restrict__ wlist)
{
    const int s = blockIdx.x * 256 + threadIdx.x;
    float lgv[E];
#pragma unroll
    for (int i = 0; i < E; ++i) lgv[i] = 0.f;
#pragma unroll
    for (int ks = 0; ks < KSLICES; ++ks) {
        const float4* p = (const float4*)(lgpart + ((size_t)ks * S + s) * E);
#pragma unroll
        for (int q = 0; q < 4; ++q) {
            float4 v = p[q];
            lgv[q * 4 + 0] += v.x; lgv[q * 4 + 1] += v.y;
            lgv[q * 4 + 2] += v.z; lgv[q * 4 + 3] += v.w;
        }
    }
    float sc[E], sb[E];
#pragma unroll
    for (int e2 = 0; e2 < E; ++e2) {
        sc[e2] = 1.f / (1.f + __expf(-lgv[e2]));
        sb[e2] = sc[e2] + bias[e2];
    }
    float gsc[GNUM];
#pragma unroll
    for (int g = 0; g < GNUM; ++g) {
        int b_ = g * EPG;
        int m1 = 0; float v1 = sb[b_];
#pragma unroll
        for (int j = 1; j < EPG; ++j) if (sb[b_ + j] > v1) { v1 = sb[b_ + j]; m1 = j; }
        float v2 = -1e30f;
#pragma unroll
        for (int j = 0; j < EPG; ++j) if (j != m1 && sb[b_ + j] > v2) v2 = sb[b_ + j];
        gsc[g] = v1 + v2;
    }
    int g1 = 0;
#pragma unroll
    for (int g = 1; g < GNUM; ++g) if (gsc[g] > gsc[g1]) g1 = g;
    int g2 = (g1 == 0) ? 1 : 0;
#pragma unroll
    for (int g = 0; g < GNUM; ++g) if (g != g1 && gsc[g] > gsc[g2]) g2 = g;
    bool allowed[E];
#pragma unroll
    for (int e2 = 0; e2 < E; ++e2) {
        int g = e2 >> 2;
        allowed[e2] = (g == g1) || (g == g2);
    }
    int idx[TOPK]; float wk[TOPK];
#pragma unroll
    for (int k = 0; k < TOPK; ++k) {
        int best = 0; float bv = -1e30f;
#pragma unroll
        for (int e2 = 0; e2 < E; ++e2)
            if (allowed[e2] && sb[e2] > bv) { bv = sb[e2]; best = e2; }
        allowed[best] = false;
        idx[k] = best;
        wk[k] = sc[best];
    }
    float inv = 1.f / (wk[0] + wk[1] + wk[2] + wk[3] + 1e-20f);
#pragma unroll
    for (int k = 0; k < TOPK; ++k) {
        int ee = idx[k];
        int pos = atomicAdd(&counts[ee], 1);
        list[ee * S + pos] = s | (k << 16);
        wlist[ee * S + pos] = wk[k] * inv;
    }
}

// ---------------------------------------------------------------------------
// K2: merged fp32 -> bf16 cast of 3 equal-size (2M elem) weight buffers.
// ---------------------------------------------------------------------------
struct CastArgs {
    const float4* src[3];
    unsigned long long* dst[3];
};
__global__ __launch_bounds__(256) void cast_bf16_x3(CastArgs a, int n4)
{
    int i = blockIdx.x * 256 + threadIdx.x;
    if (i >= n4) return;
    const float4* src = a.src[blockIdx.y];
    a.dst[blockIdx.y][i] = pack4(src[i]);
}

// ---------------------------------------------------------------------------
// K3: tiled transpose + cast: src [z][R][Cc] fp32 -> dst [z][Cc][R] bf16.
// ---------------------------------------------------------------------------
__global__ __launch_bounds__(256) void transpose_cast2(
    const float* __restrict__ srcA, unsigned short* __restrict__ dstA,
    const float* __restrict__ srcB, unsigned short* __restrict__ dstB,
    int R, int Cc, int nz)
{
    __shared__ float t[32][33];
    int z = blockIdx.z;
    const float* src = (z < nz) ? srcA : srcB;
    unsigned short* dst = (z < nz) ? dstA : dstB;
    if (z >= nz) z -= nz;
    const size_t mo = (size_t)z * R * Cc;
    src += mo; dst += mo;
    const int c0 = blockIdx.x * 32, r0 = blockIdx.y * 32;
    const int tx = threadIdx.x, ty = threadIdx.y;  // (32, 8)
#pragma unroll
    for (int i = 0; i < 32; i += 8)
        t[ty + i][tx] = src[(size_t)(r0 + ty + i) * Cc + c0 + tx];
    __syncthreads();
#pragma unroll
    for (int i = 0; i < 32; i += 8)
        dst[(size_t)(c0 + ty + i) * R + r0 + tx] = f2bf(t[tx][ty + i]);
}

// ---------------------------------------------------------------------------
// m97-style MFMA GEMMs (round-7 tile config): global_load_lds(16B) staging,
// unpadded [rows][32] LDS, XOR seg swizzle, 2-barrier K-loop.
// ---------------------------------------------------------------------------

// K4: shared gate+up fused SwiGLU -> shb bf16 [S][HS]. BM=128/BN=64.
// grid (HS/64=32, S/128=16).
__global__ __launch_bounds__(256) void gemm_shared_gateup(
    const unsigned short* __restrict__ xb, const unsigned short* __restrict__ gb,
    const unsigned short* __restrict__ ub, unsigned short* __restrict__ shb)
{
    __shared__ __align__(16) unsigned short As[128 * 32];
    __shared__ __align__(16) unsigned short Bg[64 * 32];
    __shared__ __align__(16) unsigned short Bu[64 * 32];
    const int tid = threadIdx.x;
    const int lane = tid & 63, w = tid >> 6;
    const int l15 = lane & 15, q = lane >> 4;
    const int r0 = blockIdx.y * 128;
    const int c0 = blockIdx.x * 64;
    const int wr = (w >> 1) * 64, wc = (w & 1) * 32;
    const int Lrow = lane >> 2;
    const int gseg = (lane & 3) ^ ((lane >> 3) & 3);
    const unsigned short* gA1 = xb + (size_t)(r0 + w * 16 + Lrow) * CDIM + gseg * 8;
    const unsigned short* gA2 = gA1 + (size_t)64 * CDIM;
    const unsigned short* gG  = gb + (size_t)(c0 + w * 16 + Lrow) * CDIM + gseg * 8;
    const unsigned short* gU  = ub + (size_t)(c0 + w * 16 + Lrow) * CDIM + gseg * 8;
    unsigned short* lA1 = &As[(w * 16) * 32];
    unsigned short* lA2 = lA1 + 64 * 32;
    unsigned short* lG  = &Bg[(w * 16) * 32];
    unsigned short* lU  = &Bu[(w * 16) * 32];
    const int swq = (q ^ ((l15 >> 1) & 3)) * 8;
    facc_t accg[4][2], accu[4][2];
#pragma unroll
    for (int i = 0; i < 4; ++i)
#pragma unroll
        for (int j = 0; j < 2; ++j) { accg[i][j] = 0.f; accu[i][j] = 0.f; }
    for (int k0 = 0; k0 < CDIM; k0 += 32) {
        stage16(gA1 + k0, lA1, lane);
        stage16(gA2 + k0, lA2, lane);
        stage16(gG + k0, lG, lane);
        stage16(gU + k0, lU, lane);
        __syncthreads();
        bfrag_t af[4], gf[2], uf[2];
#pragma unroll
        for (int i = 0; i < 4; ++i)
            af[i] = *(const bfrag_t*)&As[(wr + i * 16 + l15) * 32 + swq];
#pragma unroll
        for (int j = 0; j < 2; ++j) {
            gf[j] = *(const bfrag_t*)&Bg[(wc + j * 16 + l15) * 32 + swq];
            uf[j] = *(const bfrag_t*)&Bu[(wc + j * 16 + l15) * 32 + swq];
        }
#pragma unroll
        for (int i = 0; i < 4; ++i)
#pragma unroll
            for (int j = 0; j < 2; ++j) {
                accg[i][j] = __builtin_amdgcn_mfma_f32_16x16x32_bf16(af[i], gf[j], accg[i][j], 0, 0, 0);
                accu[i][j] = __builtin_amdgcn_mfma_f32_16x16x32_bf16(af[i], uf[j], accu[i][j], 0, 0, 0);
            }
        __syncthreads();
    }
#pragma unroll
    for (int i = 0; i < 4; ++i)
#pragma unroll
        for (int j = 0; j < 2; ++j)
#pragma unroll
            for (int r = 0; r < 4; ++r) {
                int row = r0 + wr + i * 16 + q * 4 + r;
                int col = c0 + wc + j * 16 + l15;
                float g = accg[i][j][r], u = accu[i][j][r];
                shb[(size_t)row * HS + col] = f2bf(g * sigmoidf_(g) * u);
            }
}

// K5: shared down-proj + routed-sum epilogue -> out fp32 [S][CDIM].
// BM=64/BN=64, K=HS. grid (CDIM/64=16, S/64=32). RUNS LAST:
// out[row][col] = acc + sum_k dbuf[row*4+k][col].
__global__ __launch_bounds__(256) void gemm_shared_down(
    const unsigned short* __restrict__ shb, const unsigned short* __restrict__ db,
    const unsigned short* __restrict__ dbuf, float* __restrict__ out)
{
    __shared__ __align__(16) unsigned short As[64 * 32];
    __shared__ __align__(16) unsigned short Bs[64 * 32];
    const int tid = threadIdx.x;
    const int lane = tid & 63, w = tid >> 6;
    const int l15 = lane & 15, q = lane >> 4;
    const int r0 = blockIdx.y * 64;
    const int c0 = blockIdx.x * 64;
    const int wr = (w >> 1) * 32, wc = (w & 1) * 32;
    const int Lrow = lane >> 2;
    const int gseg = (lane & 3) ^ ((lane >> 3) & 3);
    const unsigned short* gA = shb + (size_t)(r0 + w * 16 + Lrow) * HS + gseg * 8;
    const unsigned short* gB = db + (size_t)(c0 + w * 16 + Lrow) * HS + gseg * 8;
    unsigned short* lA = &As[(w * 16) * 32];
    unsigned short* lB = &Bs[(w * 16) * 32];
    const int swq = (q ^ ((l15 >> 1) & 3)) * 8;
    facc_t acc[2][2];
#pragma unroll
    for (int i = 0; i < 2; ++i)
#pragma unroll
        for (int j = 0; j < 2; ++j) acc[i][j] = 0.f;
    for (int k0 = 0; k0 < HS; k0 += 32) {
        stage16(gA + k0, lA, lane);
        stage16(gB + k0, lB, lane);
        __syncthreads();
        bfrag_t af[2], bf[2];
#pragma unroll
        for (int i = 0; i < 2; ++i) af[i] = *(const bfrag_t*)&As[(wr + i * 16 + l15) * 32 + swq];
#pragma unroll
        for (int j = 0; j < 2; ++j) bf[j] = *(const bfrag_t*)&Bs[(wc + j * 16 + l15) * 32 + swq];
#pragma unroll
        for (int i = 0; i < 2; ++i)
#pragma unroll
            for (int j = 0; j < 2; ++j)
                acc[i][j] = __builtin_amdgcn_mfma_f32_16x16x32_bf16(af[i], bf[j], acc[i][j], 0, 0, 0);
        __syncthreads();
    }
#pragma unroll
    for (int i = 0; i < 2; ++i)
#pragma unroll
        for (int j = 0; j < 2; ++j)
#pragma unroll
            for (int r = 0; r < 4; ++r) {
                int row = r0 + wr + i * 16 + q * 4 + r;
                int col = c0 + wc + j * 16 + l15;
                float v = acc[i][j][r];
                const unsigned short* dp = dbuf + ((size_t)row * TOPK) * CDIM + col;
#pragma unroll
                for (int k = 0; k < TOPK; ++k) v += bf2f(dp[(size_t)k * CDIM]);
                out[(size_t)row * CDIM + col] = v;
            }
}

// K6: routed gate+up, gathered A rows, weighted SwiGLU -> hbuf bf16 [S*4][H].
// BM=64/BN=64. grid (E, H/64=4, S/64=32); expert-major for XCD L2.
__global__ __launch_bounds__(256) void gemm_routed_gateup(
    const unsigned short* __restrict__ xb, const unsigned short* __restrict__ gwT,
    const unsigned short* __restrict__ uwT, const int* __restrict__ counts,
    const int* __restrict__ list, const float* __restrict__ wlist,
    unsigned short* __restrict__ hbuf)
{
    const int e = blockIdx.x;
    const int n = counts[e];
    const int t0 = blockIdx.z * 64;
    if (t0 >= n) return;
    const int h0 = blockIdx.y * 64;
    __shared__ int toks[64];
    __shared__ int hrw[64];
    __shared__ float wv[64];
    __shared__ __align__(16) unsigned short As[64 * 32];
    __shared__ __align__(16) unsigned short Bg[64 * 32];
    __shared__ __align__(16) unsigned short Bu[64 * 32];
    const int tid = threadIdx.x;
    if (tid < 64) {
        int p = t0 + tid;
        if (p < n) {
            int pk = list[e * S + p];
            toks[tid] = pk & 0xFFFF;
            hrw[tid] = (pk & 0xFFFF) * TOPK + (pk >> 16);
            wv[tid] = wlist[e * S + p];
        } else { toks[tid] = 0; hrw[tid] = 0; wv[tid] = 0.f; }
    }
    __syncthreads();
    const int lane = tid & 63, w = tid >> 6;
    const int l15 = lane & 15, q = lane >> 4;
    const int wr = (w >> 1) * 32, wc = (w & 1) * 32;
    const int Lrow = lane >> 2;
    const int gseg = (lane & 3) ^ ((lane >> 3) & 3);
    const int tokA = toks[w * 16 + Lrow];        // per-lane gathered A row
    const unsigned short* gA = xb + (size_t)tokA * CDIM + gseg * 8;
    const unsigned short* gG = gwT + ((size_t)e * H + h0 + w * 16 + Lrow) * CDIM + gseg * 8;
    const unsigned short* gU = uwT + ((size_t)e * H + h0 + w * 16 + Lrow) * CDIM + gseg * 8;
    unsigned short* lA = &As[(w * 16) * 32];
    unsigned short* lG = &Bg[(w * 16) * 32];
    unsigned short* lU = &Bu[(w * 16) * 32];
    const int swq = (q ^ ((l15 >> 1) & 3)) * 8;
    facc_t accg[2][2], accu[2][2];
#pragma unroll
    for (int i = 0; i < 2; ++i)
#pragma unroll
        for (int j = 0; j < 2; ++j) { accg[i][j] = 0.f; accu[i][j] = 0.f; }
    for (int k0 = 0; k0 < CDIM; k0 += 32) {
        stage16(gA + k0, lA, lane);
        stage16(gG + k0, lG, lane);
        stage16(gU + k0, lU, lane);
        __syncthreads();
        bfrag_t af[2], gf[2], uf[2];
#pragma unroll
        for (int i = 0; i < 2; ++i) af[i] = *(const bfrag_t*)&As[(wr + i * 16 + l15) * 32 + swq];
#pragma unroll
        for (int j = 0; j < 2; ++j) {
            gf[j] = *(const bfrag_t*)&Bg[(wc + j * 16 + l15) * 32 + swq];
            uf[j] = *(const bfrag_t*)&Bu[(wc + j * 16 + l15) * 32 + swq];
        }
#pragma unroll
        for (int i = 0; i < 2; ++i)
#pragma unroll
            for (int j = 0; j < 2; ++j) {
                accg[i][j] = __builtin_amdgcn_mfma_f32_16x16x32_bf16(af[i], gf[j], accg[i][j], 0, 0, 0);
                accu[i][j] = __builtin_amdgcn_mfma_f32_16x16x32_bf16(af[i], uf[j], accu[i][j], 0, 0, 0);
            }
        __syncthreads();
    }
#pragma unroll
    for (int i = 0; i < 2; ++i)
#pragma unroll
        for (int j = 0; j < 2; ++j)
#pragma unroll
            for (int r = 0; r < 4; ++r) {
                int li = wr + i * 16 + q * 4 + r;
                if (t0 + li < n) {
                    int col = h0 + wc + j * 16 + l15;
                    float g = accg[i][j][r], u = accu[i][j][r];
                    hbuf[(size_t)hrw[li] * H + col] = f2bf(wv[li] * g * sigmoidf_(g) * u);
                }
            }
}

// K7: routed down-proj -> dbuf bf16 [S*4][CDIM]. BM=64/BN=64, K=H=256.
// grid (E, CDIM/64=16, S/64=32); expert-major for XCD L2.
__global__ __launch_bounds__(256) void gemm_routed_down(
    const unsigned short* __restrict__ hbuf, const unsigned short* __restrict__ dwT,
    const int* __restrict__ counts, const int* __restrict__ list,
    unsigned short* __restrict__ dbuf)
{
    const int e = blockIdx.x;
    const int n = counts[e];
    const int t0 = blockIdx.z * 64;
    if (t0 >= n) return;
    const int c0 = blockIdx.y * 64;
    __shared__ int hrw[64];
    __shared__ __align__(16) unsigned short As[64 * 32];
    __shared__ __align__(16) unsigned short Bs[64 * 32];
    const int tid = threadIdx.x;
    if (tid < 64) {
        int p = t0 + tid;
        int pk = (p < n) ? list[e * S + p] : 0;
        hrw[tid] = (pk & 0xFFFF) * TOPK + (pk >> 16);
    }
    __syncthreads();
    const int lane = tid & 63, w = tid >> 6;
    const int l15 = lane & 15, q = lane >> 4;
    const int wr = (w >> 1) * 32, wc = (w & 1) * 32;
    const int Lrow = lane >> 2;
    const int gseg = (lane & 3) ^ ((lane >> 3) & 3);
    const int arow = hrw[w * 16 + Lrow];
    const unsigned short* gA = hbuf + (size_t)arow * H + gseg * 8;
    const unsigned short* gB = dwT + ((size_t)e * CDIM + c0 + w * 16 + Lrow) * H + gseg * 8;
    unsigned short* lA = &As[(w * 16) * 32];
    unsigned short* lB = &Bs[(w * 16) * 32];
    const int swq = (q ^ ((l15 >> 1) & 3)) * 8;
    facc_t acc[2][2];
#pragma unroll
    for (int i = 0; i < 2; ++i)
#pragma unroll
        for (int j = 0; j < 2; ++j) acc[i][j] = 0.f;
    for (int k0 = 0; k0 < H; k0 += 32) {
        stage16(gA + k0, lA, lane);
        stage16(gB + k0, lB, lane);
        __syncthreads();
        bfrag_t af[2], bf[2];
#pragma unroll
        for (int i = 0; i < 2; ++i) af[i] = *(const bfrag_t*)&As[(wr + i * 16 + l15) * 32 + swq];
#pragma unroll
        for (int j = 0; j < 2; ++j) bf[j] = *(const bfrag_t*)&Bs[(wc + j * 16 + l15) * 32 + swq];
#pragma unroll
        for (int i = 0; i < 2; ++i)
#pragma unroll
            for (int j = 0; j < 2; ++j)
                acc[i][j] = __builtin_amdgcn_mfma_f32_16x16x32_bf16(af[i], bf[j], acc[i][j], 0, 0, 0);
        __syncthreads();
    }
#pragma unroll
    for (int i = 0; i < 2; ++i)
#pragma unroll
        for (int j = 0; j < 2; ++j)
#pragma unroll
            for (int r = 0; r < 4; ++r) {
                int li = wr + i * 16 + q * 4 + r;
                if (t0 + li < n) {
                    int col = c0 + wc + j * 16 + l15;
                    dbuf[(size_t)hrw[li] * CDIM + col] = f2bf(acc[i][j][r]);
                }
            }
}

// ---------------------------------------------------------------------------
extern "C" void kernel_launch(void* const* d_in, const int* in_sizes, int n_in,
                              void* d_out, int out_size, void* d_ws, size_t ws_size,
                              hipStream_t stream)
{
    const float* x        = (const float*)d_in[0];
    const float* router_w = (const float*)d_in[1];
    const float* bias     = (const float*)d_in[2];
    const float* gate_w   = (const float*)d_in[3];
    const float* up_w     = (const float*)d_in[4];
    const float* down_w   = (const float*)d_in[5];
    const float* sgw      = (const float*)d_in[6];
    const float* suw      = (const float*)d_in[7];
    const float* sdw      = (const float*)d_in[8];
    float* out = (float*)d_out;

    char* ws = (char*)d_ws;
    size_t off = 0;
    int* counts = (int*)(ws + off);            off += 256;
    int* list   = (int*)(ws + off);            off += (size_t)E * S * 4;
    float* wlist = (float*)(ws + off);         off += (size_t)E * S * 4;
    unsigned short* xb  = (unsigned short*)(ws + off); off += (size_t)S * CDIM * 2;
    unsigned short* sgb = (unsigned short*)(ws + off); off += (size_t)HS * CDIM * 2;
    unsigned short* sub = (unsigned short*)(ws + off); off += (size_t)HS * CDIM * 2;
    unsigned short* sdb = (unsigned short*)(ws + off); off += (size_t)CDIM * HS * 2;
    unsigned short* gwT = (unsigned short*)(ws + off); off += (size_t)E * H * CDIM * 2;
    unsigned short* uwT = (unsigned short*)(ws + off); off += (size_t)E * H * CDIM * 2;
    unsigned short* dwT = (unsigned short*)(ws + off); off += (size_t)E * CDIM * H * 2;
    unsigned short* shb = (unsigned short*)(ws + off); off += (size_t)S * HS * 2;
    unsigned short* hbuf = (unsigned short*)(ws + off); off += (size_t)S * TOPK * H * 2;
    unsigned short* dbuf = (unsigned short*)(ws + off); off += (size_t)S * TOPK * CDIM * 2;
    // lgpart (8*S*E floats = 1 MiB) aliases dbuf (consumed by route_kernel
    // before gemm_routed_down writes dbuf; same stream, serial).
    float* lgpart = (float*)dbuf;

    hipMemsetAsync(counts, 0, E * sizeof(int), stream);
    logits_kernel<<<dim3(S / 16, KSLICES), 256, 0, stream>>>(x, router_w, lgpart, xb);
    route_kernel<<<S / 256, 256, 0, stream>>>(lgpart, bias, counts, list, wlist);

    CastArgs ca;
    ca.src[0] = (const float4*)sgw; ca.dst[0] = (unsigned long long*)sgb;
    ca.src[1] = (const float4*)suw; ca.dst[1] = (unsigned long long*)sub;
    ca.src[2] = (const float4*)sdw; ca.dst[2] = (unsigned long long*)sdb;
    cast_bf16_x3<<<dim3(HS * CDIM / 4 / 256, 3), 256, 0, stream>>>(ca, HS * CDIM / 4);

    transpose_cast2<<<dim3(H / 32, CDIM / 32, 2 * E), dim3(32, 8), 0, stream>>>(
        gate_w, gwT, up_w, uwT, CDIM, H, E);
    transpose_cast2<<<dim3(CDIM / 32, H / 32, E), dim3(32, 8), 0, stream>>>(
        down_w, dwT, down_w, dwT, H, CDIM, E);

    gemm_shared_gateup<<<dim3(HS / 64, S / 128), 256, 0, stream>>>(xb, sgb, sub, shb);
    gemm_routed_gateup<<<dim3(E, H / 64, S / 64), 256, 0, stream>>>(xb, gwT, uwT, counts, list, wlist, hbuf);
    gemm_routed_down<<<dim3(E, CDIM / 64, S / 64), 256, 0, stream>>>(hbuf, dwT, counts, list, dbuf);
    // LAST: shared down-proj with fused routed-sum epilogue (reads dbuf).
    gemm_shared_down<<<dim3(CDIM / 64, S / 64), 256, 0, stream>>>(shb, sdb, dbuf, out);
}